// Round 4
// baseline (486.387 us; speedup 1.0000x reference)
//
#include <hip/hip_runtime.h>

// QuadraticBaseMorpho: out[h][w] = max_{dy,dx in [-3,3]} xpad[h+dy][w+dx] + nb[dy+3][dx+3]
// xpad = x padded with -10000. nb = -(se/se.max()) with center forced to -10000.
// se = k1*xg^2 + 2*k2*xg*yg + k3*yg^2 is even-symmetric -> the [::-1,::-1] flip is identity.
// Input (8,64,256,256) fp32 = 512 planes of 256x256.

#define MAXV 10000.0f

constexpr int H = 256;
constexpr int W = 256;
constexpr int TILE_ROWS = 16;              // output rows per block
constexpr int LDS_ROWS = TILE_ROWS + 6;    // 22
constexpr int LDS_STRIDE = 264;            // 4 left halo + 256 data + 4 right; 1056 B rows
constexpr int ROW_TILES = H / TILE_ROWS;   // 16
constexpr int R = 4;                       // output rows per thread

typedef float vfloat4 __attribute__((ext_vector_type(4)));  // native vec for nt-store

__device__ __forceinline__ void load_lds16(const float* g, float* l) {
  // 64 lanes x 16 B -> LDS at (wave-uniform base) + lane*16  [m97 pattern]
  __builtin_amdgcn_global_load_lds(
      (const __attribute__((address_space(1))) void*)g,
      (__attribute__((address_space(3))) void*)l, 16, 0, 0);
}

__global__ __launch_bounds__(256, 6) void morpho_kernel(
    const float* __restrict__ x,
    const float* __restrict__ k1p,
    const float* __restrict__ k2p,
    const float* __restrict__ k3p,
    float* __restrict__ out) {
  __shared__ __align__(16) float tile[LDS_ROWS * LDS_STRIDE];

  const int tid = threadIdx.x;
  const int lane = tid & 63;
  const int wid = tid >> 6;                      // wave 0..3
  const int p = blockIdx.x >> 4;                 // plane (512)
  const int ty0 = (blockIdx.x & 15) * TILE_ROWS; // first output row of tile

  const float* __restrict__ xp = x + (size_t)p * (H * W);
  float* __restrict__ op = out + (size_t)p * (H * W);

  // ---- issue staging DMA first: global -> LDS, one row chunk per wave-instr ----
  for (int r = wid; r < LDS_ROWS; r += 4) {
    const int gy = ty0 - 3 + r;
    float* ldst = &tile[r * LDS_STRIDE + 4];     // wave-uniform LDS base
    if ((unsigned)gy < (unsigned)H) {            // wave-uniform branch
      load_lds16(&xp[gy * W + lane * 4], ldst);
    } else {
      vfloat4 mv = {-MAXV, -MAXV, -MAXV, -MAXV};
      *reinterpret_cast<vfloat4*>(ldst + lane * 4) = mv;
    }
  }

  // ---- halo cols 0..3 / 260..263 are always out-of-range -> -MAXV ----
  if (tid < LDS_ROWS * 8) {
    const int h = tid & 7;
    const int col = (h < 4) ? h : (256 + h);
    tile[(tid >> 3) * LDS_STRIDE + col] = -MAXV;
  }

  // ---- SE while the DMA flies: one weight per lane (8x8 grid), readlane -> SGPRs ----
  const float k1v = k1p[0], k2v = k2p[0], k3v = k3p[0];
  const int a = lane >> 3, b = lane & 7;
  const float xg = (float)(((b < 6) ? b : 6) - 3);   // clamp dup lanes; max unaffected
  const float yg = (float)(((a < 6) ? a : 6) - 3);
  const float sev = k1v * (xg * xg) + 2.0f * k2v * (xg * yg) + k3v * (yg * yg);
  float mx = sev;
#pragma unroll
  for (int off = 32; off; off >>= 1) mx = fmaxf(mx, __shfl_xor(mx, off, 64));
  const float wv = 0.0f - sev * (1.0f / mx);

  float w[49];
#pragma unroll
  for (int i = 0; i < 49; ++i) {
    const int src = (i / 7) * 8 + (i % 7);       // compile-time lane index
    w[i] = __int_as_float(__builtin_amdgcn_readlane(__float_as_int(wv), src));
  }
  w[24] = -MAXV;                                 // masked center

  __syncthreads();

  // ---- compute: lane-contiguous b128 reads; thread owns 4 cols x 4 rows ----
  const int r0 = wid * R;                        // output row base within tile

  float acc[R][4];
#pragma unroll
  for (int t = 0; t < R; ++t)
#pragma unroll
    for (int c = 0; c < 4; ++c) acc[t][c] = -INFINITY;

#pragma unroll
  for (int iy = 0; iy < R + 6; ++iy) {           // LDS rows r0 .. r0+9
    const float* rp = &tile[(r0 + iy) * LDS_STRIDE + lane * 4];
    float buf[12];
#pragma unroll
    for (int q = 0; q < 3; ++q) {
      const vfloat4 v = *reinterpret_cast<const vfloat4*>(rp + 4 * q);
      buf[4 * q + 0] = v.x;
      buf[4 * q + 1] = v.y;
      buf[4 * q + 2] = v.z;
      buf[4 * q + 3] = v.w;
    }
#pragma unroll
    for (int t = 0; t < R; ++t) {
      const int dyr = iy - t;                    // nb row index = dy+3
      if (dyr < 0 || dyr > 6) continue;          // dead after unroll
#pragma unroll
      for (int c = 0; c < 4; ++c) {
        // out col = lane*4+c uses gx lane*4+c-3..+3 -> buf[c+1..c+7]
        const float s0 = buf[c + 1] + w[dyr * 7 + 0];
        const float s1 = buf[c + 2] + w[dyr * 7 + 1];
        const float s2 = buf[c + 3] + w[dyr * 7 + 2];
        const float s3 = buf[c + 4] + w[dyr * 7 + 3];
        const float s4 = buf[c + 5] + w[dyr * 7 + 4];
        const float s5 = buf[c + 6] + w[dyr * 7 + 5];
        const float s6 = buf[c + 7] + w[dyr * 7 + 6];
        const float m0 = fmaxf(fmaxf(s0, s1), s2);     // v_max3
        const float m1 = fmaxf(fmaxf(s3, s4), s5);     // v_max3
        const float m01 = fmaxf(m0, m1);
        acc[t][c] = fmaxf(acc[t][c], fmaxf(m01, s6));  // v_max3(acc, m01, s6)
      }
    }
  }

  // ---- store: nontemporal float4, lane-contiguous (1024 B per wave-store) ----
#pragma unroll
  for (int t = 0; t < R; ++t) {
    const int gy = ty0 + r0 + t;
    vfloat4 v;
    v.x = acc[t][0];
    v.y = acc[t][1];
    v.z = acc[t][2];
    v.w = acc[t][3];
    __builtin_nontemporal_store(v, reinterpret_cast<vfloat4*>(&op[gy * W + lane * 4]));
  }
}

extern "C" void kernel_launch(void* const* d_in, const int* in_sizes, int n_in,
                              void* d_out, int out_size, void* d_ws, size_t ws_size,
                              hipStream_t stream) {
  const float* x = (const float*)d_in[0];
  const float* k1 = (const float*)d_in[1];
  const float* k2 = (const float*)d_in[2];
  const float* k3 = (const float*)d_in[3];
  float* outp = (float*)d_out;

  const int planes = 8 * 64;                     // 512
  const int blocks = planes * ROW_TILES;         // 8192
  morpho_kernel<<<dim3(blocks), dim3(256), 0, stream>>>(x, k1, k2, k3, outp);
}

// Round 5
// 247.327 us; speedup vs baseline: 1.9666x; 1.9666x over previous
//
#include <hip/hip_runtime.h>

// QuadraticBaseMorpho: out[h][w] = max_{dy,dx in [-3,3]} xpad[h+dy][w+dx] + nb[dy+3][dx+3]
// xpad = x padded with -10000. nb = -(se/se.max()) with center forced to -10000.
// se = k1*xg^2 + 2*k2*xg*yg + k3*yg^2 is even-symmetric -> the [::-1,::-1] flip is identity.
// Input (8,64,256,256) fp32 = 512 planes of 256x256.
//
// Structure: 2048 blocks; each block = 64 rows of one plane, processed as 4
// sub-tiles of 16 rows over a 24-row LDS ring. Sub-tile s's compute overlaps
// the global loads for sub-tile s+1 (register-staged, ds_write after barrier).

#define MAXV 10000.0f

constexpr int H = 256;
constexpr int W = 256;
constexpr int SUB = 16;              // output rows per sub-tile
constexpr int NSUB = 4;              // sub-tiles per block (64 rows)
constexpr int RING = 24;             // LDS ring rows (window 22 + 16 in flight, mod 24)
constexpr int LSTR = 264;            // floats/row: 4 left halo + 256 + 4 right
constexpr int R = 4;                 // output rows per thread

typedef float vf4 __attribute__((ext_vector_type(4)));

__global__ __launch_bounds__(256, 6) void morpho_kernel(
    const float* __restrict__ x,
    const float* __restrict__ k1p,
    const float* __restrict__ k2p,
    const float* __restrict__ k3p,
    float* __restrict__ out) {
  __shared__ __align__(16) float tile[RING * LSTR];   // 25344 B -> 6 blocks/CU

  const int tid = threadIdx.x;
  const int lane = tid & 63;
  const int wid = __builtin_amdgcn_readfirstlane(tid >> 6);  // wave id, pinned uniform
  const int p = blockIdx.x >> 2;                 // plane (512)
  const int ty0 = (blockIdx.x & 3) * 64;         // block's first output row

  const float* __restrict__ xp = x + (size_t)p * (H * W);
  float* __restrict__ op = out + (size_t)p * (H * W);

  // ---- halo cols 0..3 / 260..263: set once for all ring rows (never rewritten) ----
  if (tid < RING * 8) {
    const int h = tid & 7;
    const int col = (h < 4) ? h : (256 + h);
    tile[(tid >> 3) * LSTR + col] = -MAXV;
  }

  // ---- prologue: stage local rows 0..21 (gy = ty0-3+r); slot == local row ----
  for (int i = tid; i < 22 * 64; i += 256) {
    const int r = i >> 6;
    const int c = i & 63;
    const int gy = ty0 - 3 + r;                  // <= 210, only gy<0 needs clamp
    vf4 v;
    if (gy >= 0) {
      v = *reinterpret_cast<const vf4*>(&xp[gy * W + c * 4]);
    } else {
      v.x = v.y = v.z = v.w = -MAXV;
    }
    *reinterpret_cast<vf4*>(&tile[r * LSTR + 4 + c * 4]) = v;
  }

  // ---- SE: one weight per lane (8x8 grid), shuffle-max, readlane -> SGPRs ----
  const float k1v = k1p[0], k2v = k2p[0], k3v = k3p[0];
  const int ia = lane >> 3, ib = lane & 7;
  const float xg = (float)(((ib < 6) ? ib : 6) - 3);   // clamp dup lanes; max unaffected
  const float yg = (float)(((ia < 6) ? ia : 6) - 3);
  const float sev = k1v * (xg * xg) + 2.0f * k2v * (xg * yg) + k3v * (yg * yg);
  float mx = sev;
#pragma unroll
  for (int off = 32; off; off >>= 1) mx = fmaxf(mx, __shfl_xor(mx, off, 64));
  const float wv = 0.0f - sev * (1.0f / mx);

  float w[49];
#pragma unroll
  for (int i = 0; i < 49; ++i) {
    const int src = (i / 7) * 8 + (i % 7);       // compile-time lane index
    w[i] = __int_as_float(__builtin_amdgcn_readlane(__float_as_int(wv), src));
  }
  w[24] = -MAXV;                                 // masked center

  __syncthreads();

  // ---- sub-tile loop: compute s while next 16 rows' loads are in flight ----
#pragma unroll
  for (int s = 0; s < NSUB; ++s) {
    // issue staging loads (wave wid -> new rows wid*4..wid*4+3, lane -> chunk)
    vf4 stg[4];
    if (s < NSUB - 1) {
#pragma unroll
      for (int j = 0; j < 4; ++j) {
        const int gy = ty0 + 19 + 16 * s + wid * 4 + j;  // wave-uniform row
        if (gy < H) {
          stg[j] = *reinterpret_cast<const vf4*>(&xp[gy * W + lane * 4]);
        } else {
          stg[j].x = stg[j].y = stg[j].z = stg[j].w = -MAXV;
        }
      }
    }

    // compute sub-tile s: window = local rows 16s .. 16s+21 (mod 24)
    int sb0 = (16 * s) % 24 + wid * 4;           // compile-time % ; <= 28
    if (sb0 >= 24) sb0 -= 24;
    const float* baseA = &tile[sb0 * LSTR + lane * 4];
    const float* baseB = baseA - 24 * LSTR;
    const int thresh = 24 - sb0;                 // iy >= thresh wraps (uniform)

    float acc[R][4];
#pragma unroll
    for (int t = 0; t < R; ++t)
#pragma unroll
      for (int c = 0; c < 4; ++c) acc[t][c] = -INFINITY;

#pragma unroll
    for (int iy = 0; iy < R + 6; ++iy) {         // local rows sb0+iy (ring)
      const float* rp = ((iy >= thresh) ? baseB : baseA) + iy * LSTR;
      float buf[12];
#pragma unroll
      for (int q = 0; q < 3; ++q) {
        const vf4 v = *reinterpret_cast<const vf4*>(rp + 4 * q);
        buf[4 * q + 0] = v.x;
        buf[4 * q + 1] = v.y;
        buf[4 * q + 2] = v.z;
        buf[4 * q + 3] = v.w;
      }
#pragma unroll
      for (int t = 0; t < R; ++t) {
        const int dyr = iy - t;                  // nb row index = dy+3
        if (dyr < 0 || dyr > 6) continue;        // dead after unroll
#pragma unroll
        for (int c = 0; c < 4; ++c) {
          // out col = lane*4+c uses gx lane*4+c-3..+3 -> buf[c+1..c+7]
          const float s0 = buf[c + 1] + w[dyr * 7 + 0];
          const float s1 = buf[c + 2] + w[dyr * 7 + 1];
          const float s2 = buf[c + 3] + w[dyr * 7 + 2];
          const float s3 = buf[c + 4] + w[dyr * 7 + 3];
          const float s4 = buf[c + 5] + w[dyr * 7 + 4];
          const float s5 = buf[c + 6] + w[dyr * 7 + 5];
          const float s6 = buf[c + 7] + w[dyr * 7 + 6];
          const float m0 = fmaxf(fmaxf(s0, s1), s2);     // v_max3
          const float m1 = fmaxf(fmaxf(s3, s4), s5);     // v_max3
          const float m01 = fmaxf(m0, m1);
          acc[t][c] = fmaxf(acc[t][c], fmaxf(m01, s6));  // v_max3(acc, m01, s6)
        }
      }
    }

    // store sub-tile s (plain float4; lane-contiguous 1024 B per wave)
#pragma unroll
    for (int t = 0; t < R; ++t) {
      const int gy = ty0 + 16 * s + wid * 4 + t;
      vf4 v;
      v.x = acc[t][0];
      v.y = acc[t][1];
      v.z = acc[t][2];
      v.w = acc[t][3];
      *reinterpret_cast<vf4*>(&op[gy * W + lane * 4]) = v;
    }

    // commit staged rows into ring slots (old contents dead after barrier)
    __syncthreads();                             // all waves done reading window s
    if (s < NSUB - 1) {
#pragma unroll
      for (int j = 0; j < 4; ++j) {
        int sb = (22 + 16 * s) % 24 + wid * 4 + j;   // compile-time % ; <= 37
        if (sb >= 24) sb -= 24;
        *reinterpret_cast<vf4*>(&tile[sb * LSTR + 4 + lane * 4]) = stg[j];
      }
      __syncthreads();                           // new rows visible for s+1
    }
  }
}

extern "C" void kernel_launch(void* const* d_in, const int* in_sizes, int n_in,
                              void* d_out, int out_size, void* d_ws, size_t ws_size,
                              hipStream_t stream) {
  const float* x = (const float*)d_in[0];
  const float* k1 = (const float*)d_in[1];
  const float* k2 = (const float*)d_in[2];
  const float* k3 = (const float*)d_in[3];
  float* outp = (float*)d_out;

  const int planes = 8 * 64;                     // 512
  const int blocks = planes * 4;                 // 2048 (64 rows per block)
  morpho_kernel<<<dim3(blocks), dim3(256), 0, stream>>>(x, k1, k2, k3, outp);
}